// Round 9
// baseline (136.603 us; speedup 1.0000x reference)
//
#include <hip/hip_runtime.h>
#include <cmath>

typedef unsigned short u16;
typedef __attribute__((ext_vector_type(8))) short short8v;   // 8 bf16
typedef __attribute__((ext_vector_type(4))) float f32x4;

#define C_DIM 256
#define H_DIM 128
#define W_DIM 128
#define N_DIM (H_DIM*W_DIM)   // 16384
#define B_DIM 2
#define LN_EPSF 1e-5f

__device__ __forceinline__ u16 f2b(float f) {
  unsigned u = __float_as_uint(f);
  unsigned r = (u + 0x7fffu + ((u >> 16) & 1u)) >> 16;   // RNE
  return (u16)r;
}
__device__ __forceinline__ float b2f(u16 h) {
  return __uint_as_float(((unsigned)h) << 16);
}

// ---------------- K0: f32 -> bf16 conversion: W_val, W_out, pr_w, W_off|W_attn
__global__ __launch_bounds__(256) void k_cvt5(const float* __restrict__ w0,
      const float* __restrict__ w1, const float* __restrict__ w2,
      const float* __restrict__ w3, const float* __restrict__ w4,
      u16* __restrict__ d0, u16* __restrict__ d1, u16* __restrict__ d2,
      u16* __restrict__ d3) {
  int i = blockIdx.x*256 + threadIdx.x;   // float4 index
  const float* s; u16* d; int l;
  if (i < 16384)      { s = w0; d = d0;        l = i; }
  else if (i < 32768) { s = w1; d = d1;        l = i - 16384; }
  else if (i < 40960) { s = w2; d = d2;        l = i - 32768; }
  else if (i < 43008) { s = w3; d = d3;        l = i - 40960; }
  else if (i < 44032) { s = w4; d = d3 + 8192; l = i - 43008; }
  else return;
  float4 v = *(const float4*)&s[(size_t)l*4];
  d[l*4+0]=f2b(v.x); d[l*4+1]=f2b(v.y); d[l*4+2]=f2b(v.z); d[l*4+3]=f2b(v.w);
}

// ---------------- K1: fused LN1 + value GEMM + off/attn GEMM + softmax
// Block = 32 rows, 1024 blocks (4/CU). q lives only in LDS (swizzled).
__global__ __launch_bounds__(256) void k_fused1(const float* __restrict__ x,
      const float* __restrict__ g, const float* __restrict__ bta,
      const u16* __restrict__ wv, const float* __restrict__ bval,
      const u16* __restrict__ wab, const float* __restrict__ boff,
      const float* __restrict__ battn,
      u16* __restrict__ val, float* __restrict__ off, float* __restrict__ aw) {
  __shared__ u16  tileb[256*33];     // [c][nl] bf16, padded
  __shared__ float psum[256], psq[256];
  __shared__ float rmean[32], rstd[32];
  __shared__ u16 qls[32*256];        // [n][k], k XOR-swizzled by ((n&7)<<3)
  int t = threadIdx.x;
  int blk = blockIdx.x;
  int b = blk >> 9;
  int n0 = (blk & 511) * 32;
  // ---- LN over 32 rows
  {
    int nl = t & 31, cr = t >> 5;
    #pragma unroll 4
    for (int i = 0; i < 32; ++i) {
      int c = i*8 + cr;
      tileb[c*33 + nl] = f2b(x[((size_t)(b*C_DIM + c))*N_DIM + n0 + nl]);
    }
    __syncthreads();
    {
      int n = t & 31, j = t >> 5;
      float s = 0.f, s2 = 0.f;
      #pragma unroll 8
      for (int i = 0; i < 32; ++i) {
        float v = b2f(tileb[(j*32+i)*33 + n]);
        s += v; s2 += v*v;
      }
      psum[j*32+n] = s; psq[j*32+n] = s2;
    }
    __syncthreads();
    if (t < 32) {
      float s=0.f, s2=0.f;
      for (int j=0;j<8;++j){ s += psum[j*32+t]; s2 += psq[j*32+t]; }
      float m = s * (1.f/256.f);
      float var = s2 * (1.f/256.f) - m*m;
      rmean[t] = m; rstd[t] = rsqrtf(var + LN_EPSF);
    }
    __syncthreads();
    float gt = g[t], bt = bta[t];
    #pragma unroll 4
    for (int i = 0; i < 32; ++i) {
      float v = b2f(tileb[t*33 + i]);
      qls[i*256 + (t ^ ((i & 7) << 3))] = f2b((v - rmean[i]) * rstd[i] * gt + bt);
    }
    __syncthreads();
  }
  // ---- GEMM phase (M=32)
  int lane = t & 63, w = t >> 6;
  int l15 = lane & 15, lk = (lane >> 4) * 8;
  f32x4 acc[2][4] = {};
  f32x4 acc_oa[2] = {};
  float bias_v[4];
  #pragma unroll
  for (int oj = 0; oj < 4; ++oj) bias_v[oj] = bval[w*64 + oj*16 + l15];
  #pragma unroll
  for (int k0 = 0; k0 < 256; k0 += 32) {
    short8v af[2], bf[4];
    #pragma unroll
    for (int mi = 0; mi < 2; ++mi) {
      int n = mi*16 + l15;
      af[mi] = *(const short8v*)&qls[n*256 + ((k0 + lk) ^ ((n & 7) << 3))];
    }
    #pragma unroll
    for (int oj = 0; oj < 4; ++oj)
      bf[oj] = *(const short8v*)&wv[(size_t)(w*64 + oj*16 + l15)*256 + k0 + lk];
    #pragma unroll
    for (int mi = 0; mi < 2; ++mi)
      #pragma unroll
      for (int oj = 0; oj < 4; ++oj)
        acc[mi][oj] = __builtin_amdgcn_mfma_f32_16x16x32_bf16(af[mi], bf[oj], acc[mi][oj], 0,0,0);
    if (w < 3) {
      short8v bw = *(const short8v*)&wab[(size_t)(w*16 + l15)*256 + k0 + lk];
      #pragma unroll
      for (int mi = 0; mi < 2; ++mi)
        acc_oa[mi] = __builtin_amdgcn_mfma_f32_16x16x32_bf16(af[mi], bw, acc_oa[mi], 0,0,0);
    }
  }
  int rbase = (lane >> 4) * 4;
  #pragma unroll
  for (int mi = 0; mi < 2; ++mi)
    #pragma unroll
    for (int oj = 0; oj < 4; ++oj)
      #pragma unroll
      for (int r = 0; r < 4; ++r) {
        size_t m = (size_t)(b*N_DIM + n0 + mi*16 + rbase + r);
        int o = w*64 + oj*16 + l15;
        val[m*256 + o] = f2b(acc[mi][oj][r] + bias_v[oj]);
      }
  if (w < 2) {
    int o = w*16 + l15;
    float bv2 = boff[o];
    #pragma unroll
    for (int mi = 0; mi < 2; ++mi)
      #pragma unroll
      for (int r = 0; r < 4; ++r) {
        size_t m = (size_t)(b*N_DIM + n0 + mi*16 + rbase + r);
        off[m*32 + o] = acc_oa[mi][r] + bv2;
      }
  } else if (w == 2) {
    float bv2 = battn[l15];
    #pragma unroll
    for (int mi = 0; mi < 2; ++mi)
      #pragma unroll
      for (int r = 0; r < 4; ++r) {
        float v = acc_oa[mi][r] + bv2;
        float mx = fmaxf(v, __shfl_xor(v, 1));
        mx = fmaxf(mx, __shfl_xor(mx, 2));
        float e = expf(v - mx);
        float s = e + __shfl_xor(e, 1);
        s = s + __shfl_xor(s, 2);
        size_t m = (size_t)(b*N_DIM + n0 + mi*16 + rbase + r);
        aw[m*16 + l15] = e / s;
      }
  }
}

// ---------------- K2: fused sampling + out-GEMM + residual + LN2
// Block = 32 rows, 1024 blocks, XCD-chunked swizzle for value L2 locality.
__global__ __launch_bounds__(256) void k_sample_ln(const u16* __restrict__ value,
      const float* __restrict__ off, const float* __restrict__ aw,
      const u16* __restrict__ wo, const float* __restrict__ bo,
      const float* __restrict__ x,
      const float* __restrict__ g, const float* __restrict__ bta,
      u16* __restrict__ yt, u16* __restrict__ res) {
  __shared__ u16 sls[32*256];   // [n][c] swizzled; later f32 reduction buffer (16KB)
  __shared__ float rmean[32], rstd[32];
  int t = threadIdx.x;
  int lane = t & 63, w = t >> 6;
  int orig = blockIdx.x;                       // 1024 blocks, 1024%8==0 -> bijective
  int id = (orig & 7) * 128 + (orig >> 3);     // contiguous chunk per XCD
  int b = id >> 9;
  int n0 = (id & 511) * 32;
  int nh = lane >> 4;
  int dg = (lane & 15) * 4;
  // ---- phase A: sampling into swizzled LDS (8 rows per wave)
  #pragma unroll 1
  for (int it = 0; it < 8; ++it) {
    int rl = it*4 + w;
    int ng = n0 + rl;
    size_t bn = (size_t)b*N_DIM + ng;
    int hc = ng >> 7, wc = ng & 127;
    int vbase = b*(N_DIM*256) + nh*64 + dg;
    const float* op = &off[bn*32 + nh*8];
    const float* ap = &aw[bn*16 + nh*4];
    float acc0=0.f, acc1=0.f, acc2=0.f, acc3=0.f;
    #pragma unroll
    for (int p = 0; p < 4; ++p) {
      float ox = op[p*2+0], oy = op[p*2+1];
      float a  = ap[p];
      float px = (float)wc + ox;
      float py = (float)hc + oy;
      float x0f = floorf(px), y0f = floorf(py);
      float wx = px - x0f, wy = py - y0f;
      int x0 = (int)x0f, y0 = (int)y0f;
      int x1 = x0 + 1, y1 = y0 + 1;
      float fx0 = (1.f - wx) * ((x0 >= 0 && x0 < W_DIM) ? 1.f : 0.f);
      float fx1 = wx         * ((x1 >= 0 && x1 < W_DIM) ? 1.f : 0.f);
      float fy0 = a * (1.f - wy) * ((y0 >= 0 && y0 < H_DIM) ? 1.f : 0.f);
      float fy1 = a * wy         * ((y1 >= 0 && y1 < H_DIM) ? 1.f : 0.f);
      int xc0 = min(max(x0,0),W_DIM-1), xc1 = min(max(x1,0),W_DIM-1);
      int yc0 = min(max(y0,0),H_DIM-1), yc1 = min(max(y1,0),H_DIM-1);
      int r0 = yc0*W_DIM, r1 = yc1*W_DIM;
      {
        ushort4 v = *(const ushort4*)&value[vbase + (r0+xc0)*256];
        float wgt = fx0*fy0;
        acc0 += wgt*b2f(v.x); acc1 += wgt*b2f(v.y); acc2 += wgt*b2f(v.z); acc3 += wgt*b2f(v.w);
      }
      {
        ushort4 v = *(const ushort4*)&value[vbase + (r0+xc1)*256];
        float wgt = fx1*fy0;
        acc0 += wgt*b2f(v.x); acc1 += wgt*b2f(v.y); acc2 += wgt*b2f(v.z); acc3 += wgt*b2f(v.w);
      }
      {
        ushort4 v = *(const ushort4*)&value[vbase + (r1+xc0)*256];
        float wgt = fx0*fy1;
        acc0 += wgt*b2f(v.x); acc1 += wgt*b2f(v.y); acc2 += wgt*b2f(v.z); acc3 += wgt*b2f(v.w);
      }
      {
        ushort4 v = *(const ushort4*)&value[vbase + (r1+xc1)*256];
        float wgt = fx1*fy1;
        acc0 += wgt*b2f(v.x); acc1 += wgt*b2f(v.y); acc2 += wgt*b2f(v.z); acc3 += wgt*b2f(v.w);
      }
    }
    ushort4 o4;
    o4.x = f2b(acc0); o4.y = f2b(acc1); o4.z = f2b(acc2); o4.w = f2b(acc3);
    int k = nh*64 + dg;
    *(ushort4*)&sls[rl*256 + (k ^ ((rl & 7) << 3))] = o4;
  }
  __syncthreads();
  // ---- phase B: out-GEMM (M=32)
  int l15 = lane & 15, lk = (lane >> 4) * 8;
  int rbase = (lane >> 4) * 4;
  f32x4 acc[2][4] = {};   // [mi][oj]
  float bias_v[4], gv[4], btv[4];
  #pragma unroll
  for (int oj = 0; oj < 4; ++oj) {
    int o = w*64 + oj*16 + l15;
    bias_v[oj] = bo[o]; gv[oj] = g[o]; btv[oj] = bta[o];
  }
  #pragma unroll
  for (int k0 = 0; k0 < 256; k0 += 32) {
    short8v af[2], bf[4];
    #pragma unroll
    for (int mi = 0; mi < 2; ++mi) {
      int n = mi*16 + l15;
      af[mi] = *(const short8v*)&sls[n*256 + ((k0 + lk) ^ ((n & 7) << 3))];
    }
    #pragma unroll
    for (int oj = 0; oj < 4; ++oj)
      bf[oj] = *(const short8v*)&wo[(size_t)(w*64 + oj*16 + l15)*256 + k0 + lk];
    #pragma unroll
    for (int mi = 0; mi < 2; ++mi)
      #pragma unroll
      for (int oj = 0; oj < 4; ++oj)
        acc[mi][oj] = __builtin_amdgcn_mfma_f32_16x16x32_bf16(af[mi], bf[oj], acc[mi][oj], 0,0,0);
  }
  // ---- phase C: bias + residual x, partial LN sums
  #pragma unroll
  for (int mi = 0; mi < 2; ++mi)
    #pragma unroll
    for (int oj = 0; oj < 4; ++oj) {
      int o = w*64 + oj*16 + l15;
      const float* xp = &x[((size_t)(b*256 + o))*N_DIM + n0 + mi*16 + rbase];
      #pragma unroll
      for (int r = 0; r < 4; ++r)
        acc[mi][oj][r] += bias_v[oj] + xp[r];
    }
  __syncthreads();
  float* pred = (float*)sls;  // [0..2047]=sum[row][64], [2048..4095]=sq[row][64]
  int cidx = w*16 + l15;
  #pragma unroll
  for (int mi = 0; mi < 2; ++mi)
    #pragma unroll
    for (int r = 0; r < 4; ++r) {
      int row = mi*16 + rbase + r;
      float s  = acc[mi][0][r] + acc[mi][1][r] + acc[mi][2][r] + acc[mi][3][r];
      float s2 = acc[mi][0][r]*acc[mi][0][r] + acc[mi][1][r]*acc[mi][1][r]
               + acc[mi][2][r]*acc[mi][2][r] + acc[mi][3][r]*acc[mi][3][r];
      pred[row*64 + cidx] = s;
      pred[2048 + row*64 + cidx] = s2;
    }
  __syncthreads();
  {
    int row = t >> 3, q = t & 7;
    float s = 0.f, s2 = 0.f;
    #pragma unroll
    for (int i = 0; i < 8; ++i) {
      s  += pred[row*64 + q*8 + i];
      s2 += pred[2048 + row*64 + q*8 + i];
    }
    s  += __shfl_xor(s, 1);  s  += __shfl_xor(s, 2);  s  += __shfl_xor(s, 4);
    s2 += __shfl_xor(s2, 1); s2 += __shfl_xor(s2, 2); s2 += __shfl_xor(s2, 4);
    if (q == 0) {
      float m = s * (1.f/256.f);
      float var = s2 * (1.f/256.f) - m*m;
      rmean[row] = m; rstd[row] = rsqrtf(var + LN_EPSF);
    }
  }
  __syncthreads();
  // ---- phase D: write res (pre-LN) and yt (post-LN), both (B,C,N) bf16
  #pragma unroll
  for (int mi = 0; mi < 2; ++mi)
    #pragma unroll
    for (int oj = 0; oj < 4; ++oj) {
      int o = w*64 + oj*16 + l15;
      size_t base = ((size_t)(b*256 + o))*N_DIM + n0 + mi*16 + rbase;
      ushort4 rv, yv;
      u16 rr[4], yy[4];
      #pragma unroll
      for (int r = 0; r < 4; ++r) {
        int row = mi*16 + rbase + r;
        float v = acc[mi][oj][r];
        rr[r] = f2b(v);
        yy[r] = f2b((v - rmean[row]) * rstd[row] * gv[oj] + btv[oj]);
      }
      rv.x=rr[0]; rv.y=rr[1]; rv.z=rr[2]; rv.w=rr[3];
      yv.x=yy[0]; yv.y=yy[1]; yv.z=yy[2]; yv.w=yy[3];
      *(ushort4*)&res[base] = rv;
      *(ushort4*)&yt[base]  = yv;
    }
}

// ---------------- K3: depthwise 3x3 + SiLU gate, bf16 in -> bf16 h (B,128,N)
__global__ __launch_bounds__(256) void k_dwconv(const u16* __restrict__ yt,
     const float* __restrict__ dww, const float* __restrict__ dwb,
     u16* __restrict__ hb) {
  int t = threadIdx.x;
  int blk = blockIdx.x;        // b*8192 + c*64 + ht
  int ht = blk & 63; int c = (blk >> 6) & 127; int b = blk >> 13;
  int hh = t >> 7; int ww = t & 127;
  int h = ht*2 + hh;
  const u16* p1 = yt + ((size_t)(b*256 + c))*N_DIM;
  const u16* p2 = yt + ((size_t)(b*256 + c + 128))*N_DIM;
  float w1[9], w2[9];
  #pragma unroll
  for (int i=0;i<9;++i){ w1[i]=dww[c*9+i]; w2[i]=dww[(c+128)*9+i]; }
  float a1 = dwb[c], a2 = dwb[c+128];
  #pragma unroll
  for (int ky=0;ky<3;++ky){
    int yy = h + ky - 1;
    if (yy < 0 || yy >= H_DIM) continue;
    #pragma unroll
    for (int kx=0;kx<3;++kx){
      int xx = ww + kx - 1;
      if (xx < 0 || xx >= W_DIM) continue;
      float v1 = b2f(p1[yy*W_DIM+xx]), v2 = b2f(p2[yy*W_DIM+xx]);
      a1 += w1[ky*3+kx]*v1; a2 += w2[ky*3+kx]*v2;
    }
  }
  float sig = 1.f/(1.f+expf(-a1));
  hb[((size_t)(b*128+c))*N_DIM + h*W_DIM + ww] = f2b(a1*sig*a2);
}

// ---------------- K4: d_out = pr_w @ h + pr_b + res(bf16)  (32-n tiles, (512,2) grid)
__global__ __launch_bounds__(256) void k_prfinal_mfma(const u16* __restrict__ hsrc,
     const u16* __restrict__ pw, const float* __restrict__ prb,
     const u16* __restrict__ resb, float* __restrict__ dout) {
  __shared__ u16 hls[32*128];      // [n][k], k XOR-swizzled by ((n&7)<<3)
  int t = threadIdx.x;
  int lane = t & 63, w = t >> 6;
  int b = blockIdx.y;
  int n0 = blockIdx.x * 32;
  #pragma unroll
  for (int r = 0; r < 2; ++r) {
    int e = t + 256*r;      // 512 short8 chunks: 128 k x 4 n-chunks
    int k = e >> 2;         // 0..127
    int n8 = (e & 3) * 8;   // 0..24
    short8v v = *(const short8v*)&hsrc[((size_t)(b*128 + k))*N_DIM + n0 + n8];
    #pragma unroll
    for (int j = 0; j < 8; ++j) {
      int n = n8 + j;
      hls[n*128 + (k ^ ((n & 7) << 3))] = (u16)v[j];
    }
  }
  __syncthreads();
  int l15 = lane & 15, lk = (lane >> 4) * 8;
  f32x4 acc[4][2] = {};   // [oi][nj]
  #pragma unroll
  for (int k0 = 0; k0 < 128; k0 += 32) {
    short8v af[4], bf[2];
    #pragma unroll
    for (int oi = 0; oi < 4; ++oi)
      af[oi] = *(const short8v*)&pw[(size_t)(w*64 + oi*16 + l15)*128 + k0 + lk];
    #pragma unroll
    for (int nj = 0; nj < 2; ++nj) {
      int n = nj*16 + l15;
      bf[nj] = *(const short8v*)&hls[n*128 + ((k0 + lk) ^ ((n & 7) << 3))];
    }
    #pragma unroll
    for (int oi = 0; oi < 4; ++oi)
      #pragma unroll
      for (int nj = 0; nj < 2; ++nj)
        acc[oi][nj] = __builtin_amdgcn_mfma_f32_16x16x32_bf16(af[oi], bf[nj], acc[oi][nj], 0,0,0);
  }
  int rbase = (lane >> 4) * 4;
  #pragma unroll
  for (int oi = 0; oi < 4; ++oi)
    #pragma unroll
    for (int r = 0; r < 4; ++r) {
      int o = w*64 + oi*16 + rbase + r;
      float pb = prb[o];
      #pragma unroll
      for (int nj = 0; nj < 2; ++nj) {
        int n = n0 + nj*16 + l15;
        size_t idx = ((size_t)(b*256 + o))*N_DIM + n;
        dout[idx] = acc[oi][nj][r] + pb + b2f(resb[idx]);
      }
    }
}

extern "C" void kernel_launch(void* const* d_in, const int* in_sizes, int n_in,
                              void* d_out, int out_size, void* d_ws, size_t ws_size,
                              hipStream_t stream) {
  const float* x      = (const float*)d_in[0];
  const float* norm_g = (const float*)d_in[1];
  const float* norm_b = (const float*)d_in[2];
  const float* ffn_g  = (const float*)d_in[3];
  const float* ffn_b  = (const float*)d_in[4];
  const float* W_val  = (const float*)d_in[5];
  const float* b_val  = (const float*)d_in[6];
  const float* W_off  = (const float*)d_in[7];
  const float* b_off  = (const float*)d_in[8];
  const float* W_attn = (const float*)d_in[9];
  const float* b_attn = (const float*)d_in[10];
  const float* W_out  = (const float*)d_in[11];
  const float* b_out  = (const float*)d_in[12];
  const float* dw_w   = (const float*)d_in[13];
  const float* dw_b   = (const float*)d_in[14];
  const float* pr_w   = (const float*)d_in[15];
  const float* pr_b   = (const float*)d_in[16];
  float* outp = (float*)d_out;

  char* ws = (char*)d_ws;
  const size_t MB = 1u << 20;
  u16*   valbf  = (u16*)(ws);
  u16*   resbf  = (u16*)(ws + 17*MB);
  u16*   ytbf   = (u16*)(ws + 34*MB);
  u16*   hbuf   = (u16*)(ws + 51*MB);
  float* boffb  = (float*)(ws + 64*MB);
  float* bawb   = (float*)(ws + 69*MB);
  u16*   wvbf   = (u16*)(ws + 72*MB);
  u16*   wobf   = (u16*)(ws + 72*MB + 131072u);
  u16*   pwbf   = (u16*)(ws + 72*MB + 262144u);
  u16*   wabbf  = (u16*)(ws + 72*MB + 327680u);

  // 0. weights -> bf16
  k_cvt5<<<dim3(172), dim3(256), 0, stream>>>(W_val, W_out, pr_w, W_off, W_attn,
                                              wvbf, wobf, pwbf, wabbf);
  // 1. LN1 + value GEMM + off/attn GEMM (q stays in LDS)
  k_fused1<<<dim3(1024), dim3(256), 0, stream>>>(x, norm_g, norm_b, wvbf, b_val,
                                                 wabbf, b_off, b_attn,
                                                 valbf, boffb, bawb);
  // 2. sampling + out-GEMM + residual + LN2 (XCD-swizzled)
  k_sample_ln<<<dim3(1024), dim3(256), 0, stream>>>(valbf, boffb, bawb, wobf, b_out,
                                                    x, ffn_g, ffn_b, ytbf, resbf);
  // 3. depthwise conv + SiLU gate
  k_dwconv<<<dim3(16384), dim3(256), 0, stream>>>(ytbf, dw_w, dw_b, hbuf);
  // 4. d_out = pr_w @ h + pr_b + res
  k_prfinal_mfma<<<dim3(512, 2), dim3(256), 0, stream>>>(hbuf, pwbf, pr_b, resbf, outp);

  (void)in_sizes; (void)n_in; (void)out_size; (void)ws_size;
}

// Round 10
// 128.417 us; speedup vs baseline: 1.0637x; 1.0637x over previous
//
#include <hip/hip_runtime.h>
#include <cmath>

typedef unsigned short u16;
typedef __attribute__((ext_vector_type(8))) short short8v;   // 8 bf16
typedef __attribute__((ext_vector_type(4))) float f32x4;

#define C_DIM 256
#define H_DIM 128
#define W_DIM 128
#define N_DIM (H_DIM*W_DIM)   // 16384
#define B_DIM 2
#define LN_EPSF 1e-5f

__device__ __forceinline__ u16 f2b(float f) {
  unsigned u = __float_as_uint(f);
  unsigned r = (u + 0x7fffu + ((u >> 16) & 1u)) >> 16;   // RNE
  return (u16)r;
}
__device__ __forceinline__ float b2f(u16 h) {
  return __uint_as_float(((unsigned)h) << 16);
}

// ---------------- K0: f32 -> bf16 conversion: W_val, W_out, pr_w, W_off|W_attn
__global__ __launch_bounds__(256) void k_cvt5(const float* __restrict__ w0,
      const float* __restrict__ w1, const float* __restrict__ w2,
      const float* __restrict__ w3, const float* __restrict__ w4,
      u16* __restrict__ d0, u16* __restrict__ d1, u16* __restrict__ d2,
      u16* __restrict__ d3) {
  int i = blockIdx.x*256 + threadIdx.x;   // float4 index
  const float* s; u16* d; int l;
  if (i < 16384)      { s = w0; d = d0;        l = i; }
  else if (i < 32768) { s = w1; d = d1;        l = i - 16384; }
  else if (i < 40960) { s = w2; d = d2;        l = i - 32768; }
  else if (i < 43008) { s = w3; d = d3;        l = i - 40960; }
  else if (i < 44032) { s = w4; d = d3 + 8192; l = i - 43008; }
  else return;
  float4 v = *(const float4*)&s[(size_t)l*4];
  d[l*4+0]=f2b(v.x); d[l*4+1]=f2b(v.y); d[l*4+2]=f2b(v.z); d[l*4+3]=f2b(v.w);
}

// ---------------- K1: fused LN1 + value GEMM + off/attn GEMM + softmax (64 rows/block)
__global__ __launch_bounds__(256) void k_fused1(const float* __restrict__ x,
      const float* __restrict__ g, const float* __restrict__ bta,
      const u16* __restrict__ wv, const float* __restrict__ bval,
      const u16* __restrict__ wab, const float* __restrict__ boff,
      const float* __restrict__ battn,
      u16* __restrict__ val, float* __restrict__ off, float* __restrict__ aw) {
  __shared__ float tile[256*33];     // [c][nl] padded (one 32-n half)
  __shared__ float psum[256], psq[256];
  __shared__ float rmean[32], rstd[32];
  __shared__ u16 qls[64*256];        // [n][k], k XOR-swizzled by ((n&7)<<3)
  int t = threadIdx.x;
  int blk = blockIdx.x;
  int b = blk >> 8;
  int n0 = (blk & 255) * 64;
  for (int half = 0; half < 2; ++half) {
    int nh0 = n0 + half*32;
    int nl = t & 31, cr = t >> 5;
    #pragma unroll 4
    for (int i = 0; i < 32; ++i) {
      int c = i*8 + cr;
      tile[c*33 + nl] = x[((size_t)(b*C_DIM + c))*N_DIM + nh0 + nl];
    }
    __syncthreads();
    {
      int n = t & 31, j = t >> 5;
      float s = 0.f, s2 = 0.f;
      #pragma unroll 8
      for (int i = 0; i < 32; ++i) {
        float v = tile[(j*32+i)*33 + n];
        s += v; s2 += v*v;
      }
      psum[j*32+n] = s; psq[j*32+n] = s2;
    }
    __syncthreads();
    if (t < 32) {
      float s=0.f, s2=0.f;
      for (int j=0;j<8;++j){ s += psum[j*32+t]; s2 += psq[j*32+t]; }
      float m = s * (1.f/256.f);
      float var = s2 * (1.f/256.f) - m*m;
      rmean[t] = m; rstd[t] = rsqrtf(var + LN_EPSF);
    }
    __syncthreads();
    float gt = g[t], bt = bta[t];
    #pragma unroll 4
    for (int i = 0; i < 32; ++i) {
      float v = tile[t*33 + i];
      int n = half*32 + i;
      qls[n*256 + (t ^ ((n & 7) << 3))] = f2b((v - rmean[i]) * rstd[i] * gt + bt);
    }
    __syncthreads();
  }
  int lane = t & 63, w = t >> 6;
  int l15 = lane & 15, lk = (lane >> 4) * 8;
  f32x4 acc[4][4] = {};
  f32x4 acc_oa[4] = {};
  float bias_v[4];
  #pragma unroll
  for (int oj = 0; oj < 4; ++oj) bias_v[oj] = bval[w*64 + oj*16 + l15];
  #pragma unroll
  for (int k0 = 0; k0 < 256; k0 += 32) {
    short8v af[4], bf[4];
    #pragma unroll
    for (int mi = 0; mi < 4; ++mi) {
      int n = mi*16 + l15;
      af[mi] = *(const short8v*)&qls[n*256 + ((k0 + lk) ^ ((n & 7) << 3))];
    }
    #pragma unroll
    for (int oj = 0; oj < 4; ++oj)
      bf[oj] = *(const short8v*)&wv[(size_t)(w*64 + oj*16 + l15)*256 + k0 + lk];
    #pragma unroll
    for (int mi = 0; mi < 4; ++mi)
      #pragma unroll
      for (int oj = 0; oj < 4; ++oj)
        acc[mi][oj] = __builtin_amdgcn_mfma_f32_16x16x32_bf16(af[mi], bf[oj], acc[mi][oj], 0,0,0);
    if (w < 3) {
      short8v bw = *(const short8v*)&wab[(size_t)(w*16 + l15)*256 + k0 + lk];
      #pragma unroll
      for (int mi = 0; mi < 4; ++mi)
        acc_oa[mi] = __builtin_amdgcn_mfma_f32_16x16x32_bf16(af[mi], bw, acc_oa[mi], 0,0,0);
    }
  }
  int rbase = (lane >> 4) * 4;
  #pragma unroll
  for (int mi = 0; mi < 4; ++mi)
    #pragma unroll
    for (int oj = 0; oj < 4; ++oj)
      #pragma unroll
      for (int r = 0; r < 4; ++r) {
        size_t m = (size_t)(b*N_DIM + n0 + mi*16 + rbase + r);
        int o = w*64 + oj*16 + l15;
        val[m*256 + o] = f2b(acc[mi][oj][r] + bias_v[oj]);
      }
  if (w < 2) {
    int o = w*16 + l15;
    float bv2 = boff[o];
    #pragma unroll
    for (int mi = 0; mi < 4; ++mi)
      #pragma unroll
      for (int r = 0; r < 4; ++r) {
        size_t m = (size_t)(b*N_DIM + n0 + mi*16 + rbase + r);
        off[m*32 + o] = acc_oa[mi][r] + bv2;
      }
  } else if (w == 2) {
    float bv2 = battn[l15];
    #pragma unroll
    for (int mi = 0; mi < 4; ++mi)
      #pragma unroll
      for (int r = 0; r < 4; ++r) {
        float v = acc_oa[mi][r] + bv2;
        float mx = fmaxf(v, __shfl_xor(v, 1));
        mx = fmaxf(mx, __shfl_xor(mx, 2));
        float e = expf(v - mx);
        float s = e + __shfl_xor(e, 1);
        s = s + __shfl_xor(s, 2);
        size_t m = (size_t)(b*N_DIM + n0 + mi*16 + rbase + r);
        aw[m*16 + l15] = e / s;
      }
  }
}

// ---------------- K2: standalone deformable sampling (wave per bn), XCD-swizzled
__global__ __launch_bounds__(256) void k_sample(const u16* __restrict__ value,
      const float* __restrict__ off, const float* __restrict__ aw,
      u16* __restrict__ attn_out) {
  int t = threadIdx.x;
  int wv = t >> 6, lane = t & 63;
  int orig = blockIdx.x;                      // 8192 blocks, %8==0 -> bijective
  int id = (orig & 7) * 1024 + (orig >> 3);   // contiguous 1024-block chunk per XCD
  int bn = id*4 + wv;                         // b*N + n
  int b = bn >> 14, n = bn & (N_DIM-1);
  int hc = n >> 7, wc = n & 127;
  int nh = lane >> 4;
  int dg = (lane & 15) * 4;
  int vbase = b*(N_DIM*256) + nh*64 + dg;
  const float* op = &off[(size_t)bn*32 + nh*8];
  const float* ap = &aw[(size_t)bn*16 + nh*4];
  float acc0=0.f, acc1=0.f, acc2=0.f, acc3=0.f;
  #pragma unroll
  for (int p = 0; p < 4; ++p) {
    float ox = op[p*2+0], oy = op[p*2+1];
    float a  = ap[p];
    float px = (float)wc + ox;
    float py = (float)hc + oy;
    float x0f = floorf(px), y0f = floorf(py);
    float wx = px - x0f, wy = py - y0f;
    int x0 = (int)x0f, y0 = (int)y0f;
    int x1 = x0 + 1, y1 = y0 + 1;
    float fx0 = (1.f - wx) * ((x0 >= 0 && x0 < W_DIM) ? 1.f : 0.f);
    float fx1 = wx         * ((x1 >= 0 && x1 < W_DIM) ? 1.f : 0.f);
    float fy0 = a * (1.f - wy) * ((y0 >= 0 && y0 < H_DIM) ? 1.f : 0.f);
    float fy1 = a * wy         * ((y1 >= 0 && y1 < H_DIM) ? 1.f : 0.f);
    int xc0 = min(max(x0,0),W_DIM-1), xc1 = min(max(x1,0),W_DIM-1);
    int yc0 = min(max(y0,0),H_DIM-1), yc1 = min(max(y1,0),H_DIM-1);
    int r0 = yc0*W_DIM, r1 = yc1*W_DIM;
    {
      ushort4 v = *(const ushort4*)&value[vbase + (r0+xc0)*256];
      float wgt = fx0*fy0;
      acc0 += wgt*b2f(v.x); acc1 += wgt*b2f(v.y); acc2 += wgt*b2f(v.z); acc3 += wgt*b2f(v.w);
    }
    {
      ushort4 v = *(const ushort4*)&value[vbase + (r0+xc1)*256];
      float wgt = fx1*fy0;
      acc0 += wgt*b2f(v.x); acc1 += wgt*b2f(v.y); acc2 += wgt*b2f(v.z); acc3 += wgt*b2f(v.w);
    }
    {
      ushort4 v = *(const ushort4*)&value[vbase + (r1+xc0)*256];
      float wgt = fx0*fy1;
      acc0 += wgt*b2f(v.x); acc1 += wgt*b2f(v.y); acc2 += wgt*b2f(v.z); acc3 += wgt*b2f(v.w);
    }
    {
      ushort4 v = *(const ushort4*)&value[vbase + (r1+xc1)*256];
      float wgt = fx1*fy1;
      acc0 += wgt*b2f(v.x); acc1 += wgt*b2f(v.y); acc2 += wgt*b2f(v.z); acc3 += wgt*b2f(v.w);
    }
  }
  ushort4 o;
  o.x = f2b(acc0); o.y = f2b(acc1); o.z = f2b(acc2); o.w = f2b(acc3);
  *(ushort4*)&attn_out[(size_t)bn*256 + nh*64 + dg] = o;
}

// ---------------- K3: out-GEMM + bias + x residual + LN2 -> yt, res (64 rows/block)
__global__ __launch_bounds__(256) void k_out_ln(const u16* __restrict__ ain, // (B,N,C) bf16
      const u16* __restrict__ wo, const float* __restrict__ bo,
      const float* __restrict__ x,
      const float* __restrict__ g, const float* __restrict__ bta,
      u16* __restrict__ yt, u16* __restrict__ res) {
  __shared__ float pred[8192];          // sum[64][64] | sq[64][64]
  __shared__ float rmean[64], rstd[64];
  int t = threadIdx.x;
  int lane = t & 63, w = t >> 6;
  int blk = blockIdx.x;
  int b = blk >> 8;
  int n0 = (blk & 255) * 64;
  int l15 = lane & 15, lk = (lane >> 4) * 8;
  int rbase = (lane >> 4) * 4;
  f32x4 acc[4][4] = {};   // [mi][oj]
  float bias_v[4], gv[4], btv[4];
  #pragma unroll
  for (int oj = 0; oj < 4; ++oj) {
    int o = w*64 + oj*16 + l15;
    bias_v[oj] = bo[o]; gv[oj] = g[o]; btv[oj] = bta[o];
  }
  #pragma unroll
  for (int k0 = 0; k0 < 256; k0 += 32) {
    short8v af[4], bf[4];
    #pragma unroll
    for (int mi = 0; mi < 4; ++mi)
      af[mi] = *(const short8v*)&ain[(size_t)(b*N_DIM + n0 + mi*16 + l15)*256 + k0 + lk];
    #pragma unroll
    for (int oj = 0; oj < 4; ++oj)
      bf[oj] = *(const short8v*)&wo[(size_t)(w*64 + oj*16 + l15)*256 + k0 + lk];
    #pragma unroll
    for (int mi = 0; mi < 4; ++mi)
      #pragma unroll
      for (int oj = 0; oj < 4; ++oj)
        acc[mi][oj] = __builtin_amdgcn_mfma_f32_16x16x32_bf16(af[mi], bf[oj], acc[mi][oj], 0,0,0);
  }
  // bias + residual x
  #pragma unroll
  for (int mi = 0; mi < 4; ++mi)
    #pragma unroll
    for (int oj = 0; oj < 4; ++oj) {
      int o = w*64 + oj*16 + l15;
      const float* xp = &x[((size_t)(b*256 + o))*N_DIM + n0 + mi*16 + rbase];
      #pragma unroll
      for (int r = 0; r < 4; ++r)
        acc[mi][oj][r] += bias_v[oj] + xp[r];
    }
  // LN partial sums
  int cidx = w*16 + l15;
  #pragma unroll
  for (int mi = 0; mi < 4; ++mi)
    #pragma unroll
    for (int r = 0; r < 4; ++r) {
      int row = mi*16 + rbase + r;
      float s  = acc[mi][0][r] + acc[mi][1][r] + acc[mi][2][r] + acc[mi][3][r];
      float s2 = acc[mi][0][r]*acc[mi][0][r] + acc[mi][1][r]*acc[mi][1][r]
               + acc[mi][2][r]*acc[mi][2][r] + acc[mi][3][r]*acc[mi][3][r];
      pred[row*64 + cidx] = s;
      pred[4096 + row*64 + cidx] = s2;
    }
  __syncthreads();
  {
    int row = t >> 2, q = t & 3;
    float s = 0.f, s2 = 0.f;
    #pragma unroll
    for (int i = 0; i < 16; ++i) {
      s  += pred[row*64 + q*16 + i];
      s2 += pred[4096 + row*64 + q*16 + i];
    }
    s  += __shfl_xor(s, 1);  s  += __shfl_xor(s, 2);
    s2 += __shfl_xor(s2, 1); s2 += __shfl_xor(s2, 2);
    if (q == 0) {
      float m = s * (1.f/256.f);
      float var = s2 * (1.f/256.f) - m*m;
      rmean[row] = m; rstd[row] = rsqrtf(var + LN_EPSF);
    }
  }
  __syncthreads();
  // write res (pre-LN) and yt (post-LN), both (B,C,N) bf16
  #pragma unroll
  for (int mi = 0; mi < 4; ++mi)
    #pragma unroll
    for (int oj = 0; oj < 4; ++oj) {
      int o = w*64 + oj*16 + l15;
      size_t base = ((size_t)(b*256 + o))*N_DIM + n0 + mi*16 + rbase;
      ushort4 rv, yv;
      u16 rr[4], yy[4];
      #pragma unroll
      for (int r = 0; r < 4; ++r) {
        int row = mi*16 + rbase + r;
        float v = acc[mi][oj][r];
        rr[r] = f2b(v);
        yy[r] = f2b((v - rmean[row]) * rstd[row] * gv[oj] + btv[oj]);
      }
      rv.x=rr[0]; rv.y=rr[1]; rv.z=rr[2]; rv.w=rr[3];
      yv.x=yy[0]; yv.y=yy[1]; yv.z=yy[2]; yv.w=yy[3];
      *(ushort4*)&res[base] = rv;
      *(ushort4*)&yt[base]  = yv;
    }
}

// ---------------- K4: depthwise 3x3 + SiLU gate, bf16 in -> bf16 h (B,128,N)
__global__ __launch_bounds__(256) void k_dwconv(const u16* __restrict__ yt,
     const float* __restrict__ dww, const float* __restrict__ dwb,
     u16* __restrict__ hb) {
  int t = threadIdx.x;
  int blk = blockIdx.x;        // b*8192 + c*64 + ht
  int ht = blk & 63; int c = (blk >> 6) & 127; int b = blk >> 13;
  int hh = t >> 7; int ww = t & 127;
  int h = ht*2 + hh;
  const u16* p1 = yt + ((size_t)(b*256 + c))*N_DIM;
  const u16* p2 = yt + ((size_t)(b*256 + c + 128))*N_DIM;
  float w1[9], w2[9];
  #pragma unroll
  for (int i=0;i<9;++i){ w1[i]=dww[c*9+i]; w2[i]=dww[(c+128)*9+i]; }
  float a1 = dwb[c], a2 = dwb[c+128];
  #pragma unroll
  for (int ky=0;ky<3;++ky){
    int yy = h + ky - 1;
    if (yy < 0 || yy >= H_DIM) continue;
    #pragma unroll
    for (int kx=0;kx<3;++kx){
      int xx = ww + kx - 1;
      if (xx < 0 || xx >= W_DIM) continue;
      float v1 = b2f(p1[yy*W_DIM+xx]), v2 = b2f(p2[yy*W_DIM+xx]);
      a1 += w1[ky*3+kx]*v1; a2 += w2[ky*3+kx]*v2;
    }
  }
  float sig = 1.f/(1.f+expf(-a1));
  hb[((size_t)(b*128+c))*N_DIM + h*W_DIM + ww] = f2b(a1*sig*a2);
}

// ---------------- K5: d_out = pr_w @ h + pr_b + res(bf16)  (64-n tiles)
__global__ __launch_bounds__(256) void k_prfinal_mfma(const u16* __restrict__ hsrc,
     const u16* __restrict__ pw, const float* __restrict__ prb,
     const u16* __restrict__ resb, float* __restrict__ dout) {
  __shared__ u16 hls[64*128];      // [n][k], k XOR-swizzled by ((n&7)<<3)
  int t = threadIdx.x;
  int lane = t & 63, w = t >> 6;
  int b = blockIdx.y;
  int n0 = blockIdx.x * 64;
  #pragma unroll
  for (int r = 0; r < 4; ++r) {
    int e = t + 256*r;
    int k = e >> 3;
    int n8 = (e & 7) * 8;
    short8v v = *(const short8v*)&hsrc[((size_t)(b*128 + k))*N_DIM + n0 + n8];
    #pragma unroll
    for (int j = 0; j < 8; ++j) {
      int n = n8 + j;
      hls[n*128 + (k ^ ((n & 7) << 3))] = (u16)v[j];
    }
  }
  __syncthreads();
  int l15 = lane & 15, lk = (lane >> 4) * 8;
  f32x4 acc[4][4] = {};
  #pragma unroll
  for (int k0 = 0; k0 < 128; k0 += 32) {
    short8v af[4], bf[4];
    #pragma unroll
    for (int oi = 0; oi < 4; ++oi)
      af[oi] = *(const short8v*)&pw[(size_t)(w*64 + oi*16 + l15)*128 + k0 + lk];
    #pragma unroll
    for (int nj = 0; nj < 4; ++nj) {
      int n = nj*16 + l15;
      bf[nj] = *(const short8v*)&hls[n*128 + ((k0 + lk) ^ ((n & 7) << 3))];
    }
    #pragma unroll
    for (int oi = 0; oi < 4; ++oi)
      #pragma unroll
      for (int nj = 0; nj < 4; ++nj)
        acc[oi][nj] = __builtin_amdgcn_mfma_f32_16x16x32_bf16(af[oi], bf[nj], acc[oi][nj], 0,0,0);
  }
  int rbase = (lane >> 4) * 4;
  #pragma unroll
  for (int oi = 0; oi < 4; ++oi)
    #pragma unroll
    for (int r = 0; r < 4; ++r) {
      int o = w*64 + oi*16 + rbase + r;
      float pb = prb[o];
      #pragma unroll
      for (int nj = 0; nj < 4; ++nj) {
        int n = n0 + nj*16 + l15;
        size_t idx = ((size_t)(b*256 + o))*N_DIM + n;
        dout[idx] = acc[oi][nj][r] + pb + b2f(resb[idx]);
      }
    }
}

extern "C" void kernel_launch(void* const* d_in, const int* in_sizes, int n_in,
                              void* d_out, int out_size, void* d_ws, size_t ws_size,
                              hipStream_t stream) {
  const float* x      = (const float*)d_in[0];
  const float* norm_g = (const float*)d_in[1];
  const float* norm_b = (const float*)d_in[2];
  const float* ffn_g  = (const float*)d_in[3];
  const float* ffn_b  = (const float*)d_in[4];
  const float* W_val  = (const float*)d_in[5];
  const float* b_val  = (const float*)d_in[6];
  const float* W_off  = (const float*)d_in[7];
  const float* b_off  = (const float*)d_in[8];
  const float* W_attn = (const float*)d_in[9];
  const float* b_attn = (const float*)d_in[10];
  const float* W_out  = (const float*)d_in[11];
  const float* b_out  = (const float*)d_in[12];
  const float* dw_w   = (const float*)d_in[13];
  const float* dw_b   = (const float*)d_in[14];
  const float* pr_w   = (const float*)d_in[15];
  const float* pr_b   = (const float*)d_in[16];
  float* outp = (float*)d_out;

  char* ws = (char*)d_ws;
  const size_t MB = 1u << 20;
  u16*   valbf  = (u16*)(ws);
  u16*   attnbf = (u16*)(ws + 17*MB);
  u16*   resbf  = (u16*)(ws + 34*MB);
  u16*   ytbf   = (u16*)(ws + 51*MB);
  u16*   hbuf   = (u16*)(ws + 68*MB);
  float* boffb  = (float*)(ws + 77*MB);
  float* bawb   = (float*)(ws + 82*MB);
  u16*   wvbf   = (u16*)(ws + 85*MB);
  u16*   wobf   = (u16*)(ws + 85*MB + 131072u);
  u16*   pwbf   = (u16*)(ws + 85*MB + 262144u);
  u16*   wabbf  = (u16*)(ws + 85*MB + 327680u);

  // 0. weights -> bf16
  k_cvt5<<<dim3(172), dim3(256), 0, stream>>>(W_val, W_out, pr_w, W_off, W_attn,
                                              wvbf, wobf, pwbf, wabbf);
  // 1. LN1 + value GEMM + off/attn GEMM (q stays in LDS)
  k_fused1<<<dim3(512), dim3(256), 0, stream>>>(x, norm_g, norm_b, wvbf, b_val,
                                                wabbf, b_off, b_attn,
                                                valbf, boffb, bawb);
  // 2. standalone sampling (XCD-swizzled, high occupancy)
  k_sample<<<dim3(8192), dim3(256), 0, stream>>>(valbf, boffb, bawb, attnbf);
  // 3. out-GEMM + residual + LN2 -> yt, res
  k_out_ln<<<dim3(512), dim3(256), 0, stream>>>(attnbf, wobf, b_out,
                                                x, ffn_g, ffn_b, ytbf, resbf);
  // 4. depthwise conv + SiLU gate
  k_dwconv<<<dim3(16384), dim3(256), 0, stream>>>(ytbf, dw_w, dw_b, hbuf);
  // 5. d_out = pr_w @ h + pr_b + res
  k_prfinal_mfma<<<dim3(256, 2), dim3(256), 0, stream>>>(hbuf, pwbf, pr_b, resbf, outp);

  (void)in_sizes; (void)n_in; (void)out_size; (void)ws_size;
}

// Round 11
// 120.185 us; speedup vs baseline: 1.1366x; 1.0685x over previous
//
#include <hip/hip_runtime.h>
#include <cmath>

typedef unsigned short u16;
typedef __attribute__((ext_vector_type(8))) short short8v;   // 8 bf16
typedef __attribute__((ext_vector_type(4))) float f32x4;

#define C_DIM 256
#define H_DIM 128
#define W_DIM 128
#define N_DIM (H_DIM*W_DIM)   // 16384
#define B_DIM 2
#define LN_EPSF 1e-5f

__device__ __forceinline__ u16 f2b(float f) {
  unsigned u = __float_as_uint(f);
  unsigned r = (u + 0x7fffu + ((u >> 16) & 1u)) >> 16;   // RNE
  return (u16)r;
}
__device__ __forceinline__ float b2f(u16 h) {
  return __uint_as_float(((unsigned)h) << 16);
}

// ---------------- K0: f32 -> bf16 conversion: W_val, W_out, pr_w, W_off|W_attn
__global__ __launch_bounds__(256) void k_cvt5(const float* __restrict__ w0,
      const float* __restrict__ w1, const float* __restrict__ w2,
      const float* __restrict__ w3, const float* __restrict__ w4,
      u16* __restrict__ d0, u16* __restrict__ d1, u16* __restrict__ d2,
      u16* __restrict__ d3) {
  int i = blockIdx.x*256 + threadIdx.x;   // float4 index
  const float* s; u16* d; int l;
  if (i < 16384)      { s = w0; d = d0;        l = i; }
  else if (i < 32768) { s = w1; d = d1;        l = i - 16384; }
  else if (i < 40960) { s = w2; d = d2;        l = i - 32768; }
  else if (i < 43008) { s = w3; d = d3;        l = i - 40960; }
  else if (i < 44032) { s = w4; d = d3 + 8192; l = i - 43008; }
  else return;
  float4 v = *(const float4*)&s[(size_t)l*4];
  d[l*4+0]=f2b(v.x); d[l*4+1]=f2b(v.y); d[l*4+2]=f2b(v.z); d[l*4+3]=f2b(v.w);
}

// ---------------- K1: fused LN1 + value GEMM + off/attn GEMM + softmax (64 rows/block)
__global__ __launch_bounds__(256) void k_fused1(const float* __restrict__ x,
      const float* __restrict__ g, const float* __restrict__ bta,
      const u16* __restrict__ wv, const float* __restrict__ bval,
      const u16* __restrict__ wab, const float* __restrict__ boff,
      const float* __restrict__ battn,
      u16* __restrict__ val, float* __restrict__ off, float* __restrict__ aw) {
  __shared__ float tile[256*33];     // [c][nl] padded (one 32-n half)
  __shared__ float psum[256], psq[256];
  __shared__ float rmean[32], rstd[32];
  __shared__ u16 qls[64*256];        // [n][k], k XOR-swizzled by ((n&7)<<3)
  int t = threadIdx.x;
  int blk = blockIdx.x;
  int b = blk >> 8;
  int n0 = (blk & 255) * 64;
  for (int half = 0; half < 2; ++half) {
    int nh0 = n0 + half*32;
    int nl = t & 31, cr = t >> 5;
    #pragma unroll 4
    for (int i = 0; i < 32; ++i) {
      int c = i*8 + cr;
      tile[c*33 + nl] = x[((size_t)(b*C_DIM + c))*N_DIM + nh0 + nl];
    }
    __syncthreads();
    {
      int n = t & 31, j = t >> 5;
      float s = 0.f, s2 = 0.f;
      #pragma unroll 8
      for (int i = 0; i < 32; ++i) {
        float v = tile[(j*32+i)*33 + n];
        s += v; s2 += v*v;
      }
      psum[j*32+n] = s; psq[j*32+n] = s2;
    }
    __syncthreads();
    if (t < 32) {
      float s=0.f, s2=0.f;
      for (int j=0;j<8;++j){ s += psum[j*32+t]; s2 += psq[j*32+t]; }
      float m = s * (1.f/256.f);
      float var = s2 * (1.f/256.f) - m*m;
      rmean[t] = m; rstd[t] = rsqrtf(var + LN_EPSF);
    }
    __syncthreads();
    float gt = g[t], bt = bta[t];
    #pragma unroll 4
    for (int i = 0; i < 32; ++i) {
      float v = tile[t*33 + i];
      int n = half*32 + i;
      qls[n*256 + (t ^ ((n & 7) << 3))] = f2b((v - rmean[i]) * rstd[i] * gt + bt);
    }
    __syncthreads();
  }
  int lane = t & 63, w = t >> 6;
  int l15 = lane & 15, lk = (lane >> 4) * 8;
  f32x4 acc[4][4] = {};
  f32x4 acc_oa[4] = {};
  float bias_v[4];
  #pragma unroll
  for (int oj = 0; oj < 4; ++oj) bias_v[oj] = bval[w*64 + oj*16 + l15];
  #pragma unroll
  for (int k0 = 0; k0 < 256; k0 += 32) {
    short8v af[4], bf[4];
    #pragma unroll
    for (int mi = 0; mi < 4; ++mi) {
      int n = mi*16 + l15;
      af[mi] = *(const short8v*)&qls[n*256 + ((k0 + lk) ^ ((n & 7) << 3))];
    }
    #pragma unroll
    for (int oj = 0; oj < 4; ++oj)
      bf[oj] = *(const short8v*)&wv[(size_t)(w*64 + oj*16 + l15)*256 + k0 + lk];
    #pragma unroll
    for (int mi = 0; mi < 4; ++mi)
      #pragma unroll
      for (int oj = 0; oj < 4; ++oj)
        acc[mi][oj] = __builtin_amdgcn_mfma_f32_16x16x32_bf16(af[mi], bf[oj], acc[mi][oj], 0,0,0);
    if (w < 3) {
      short8v bw = *(const short8v*)&wab[(size_t)(w*16 + l15)*256 + k0 + lk];
      #pragma unroll
      for (int mi = 0; mi < 4; ++mi)
        acc_oa[mi] = __builtin_amdgcn_mfma_f32_16x16x32_bf16(af[mi], bw, acc_oa[mi], 0,0,0);
    }
  }
  int rbase = (lane >> 4) * 4;
  #pragma unroll
  for (int mi = 0; mi < 4; ++mi)
    #pragma unroll
    for (int oj = 0; oj < 4; ++oj)
      #pragma unroll
      for (int r = 0; r < 4; ++r) {
        size_t m = (size_t)(b*N_DIM + n0 + mi*16 + rbase + r);
        int o = w*64 + oj*16 + l15;
        val[m*256 + o] = f2b(acc[mi][oj][r] + bias_v[oj]);
      }
  if (w < 2) {
    int o = w*16 + l15;
    float bv2 = boff[o];
    #pragma unroll
    for (int mi = 0; mi < 4; ++mi)
      #pragma unroll
      for (int r = 0; r < 4; ++r) {
        size_t m = (size_t)(b*N_DIM + n0 + mi*16 + rbase + r);
        off[m*32 + o] = acc_oa[mi][r] + bv2;
      }
  } else if (w == 2) {
    float bv2 = battn[l15];
    #pragma unroll
    for (int mi = 0; mi < 4; ++mi)
      #pragma unroll
      for (int r = 0; r < 4; ++r) {
        float v = acc_oa[mi][r] + bv2;
        float mx = fmaxf(v, __shfl_xor(v, 1));
        mx = fmaxf(mx, __shfl_xor(mx, 2));
        float e = expf(v - mx);
        float s = e + __shfl_xor(e, 1);
        s = s + __shfl_xor(s, 2);
        size_t m = (size_t)(b*N_DIM + n0 + mi*16 + rbase + r);
        aw[m*16 + l15] = e / s;
      }
  }
}

// ---------------- K2: standalone deformable sampling (wave per bn), XCD-swizzled
__global__ __launch_bounds__(256) void k_sample(const u16* __restrict__ value,
      const float* __restrict__ off, const float* __restrict__ aw,
      u16* __restrict__ attn_out) {
  int t = threadIdx.x;
  int wv = t >> 6, lane = t & 63;
  int orig = blockIdx.x;                      // 8192 blocks, %8==0 -> bijective
  int id = (orig & 7) * 1024 + (orig >> 3);   // contiguous 1024-block chunk per XCD
  int bn = id*4 + wv;                         // b*N + n
  int b = bn >> 14, n = bn & (N_DIM-1);
  int hc = n >> 7, wc = n & 127;
  int nh = lane >> 4;
  int dg = (lane & 15) * 4;
  int vbase = b*(N_DIM*256) + nh*64 + dg;
  const float* op = &off[(size_t)bn*32 + nh*8];
  const float* ap = &aw[(size_t)bn*16 + nh*4];
  float acc0=0.f, acc1=0.f, acc2=0.f, acc3=0.f;
  #pragma unroll
  for (int p = 0; p < 4; ++p) {
    float ox = op[p*2+0], oy = op[p*2+1];
    float a  = ap[p];
    float px = (float)wc + ox;
    float py = (float)hc + oy;
    float x0f = floorf(px), y0f = floorf(py);
    float wx = px - x0f, wy = py - y0f;
    int x0 = (int)x0f, y0 = (int)y0f;
    int x1 = x0 + 1, y1 = y0 + 1;
    float fx0 = (1.f - wx) * ((x0 >= 0 && x0 < W_DIM) ? 1.f : 0.f);
    float fx1 = wx         * ((x1 >= 0 && x1 < W_DIM) ? 1.f : 0.f);
    float fy0 = a * (1.f - wy) * ((y0 >= 0 && y0 < H_DIM) ? 1.f : 0.f);
    float fy1 = a * wy         * ((y1 >= 0 && y1 < H_DIM) ? 1.f : 0.f);
    int xc0 = min(max(x0,0),W_DIM-1), xc1 = min(max(x1,0),W_DIM-1);
    int yc0 = min(max(y0,0),H_DIM-1), yc1 = min(max(y1,0),H_DIM-1);
    int r0 = yc0*W_DIM, r1 = yc1*W_DIM;
    {
      ushort4 v = *(const ushort4*)&value[vbase + (r0+xc0)*256];
      float wgt = fx0*fy0;
      acc0 += wgt*b2f(v.x); acc1 += wgt*b2f(v.y); acc2 += wgt*b2f(v.z); acc3 += wgt*b2f(v.w);
    }
    {
      ushort4 v = *(const ushort4*)&value[vbase + (r0+xc1)*256];
      float wgt = fx1*fy0;
      acc0 += wgt*b2f(v.x); acc1 += wgt*b2f(v.y); acc2 += wgt*b2f(v.z); acc3 += wgt*b2f(v.w);
    }
    {
      ushort4 v = *(const ushort4*)&value[vbase + (r1+xc0)*256];
      float wgt = fx0*fy1;
      acc0 += wgt*b2f(v.x); acc1 += wgt*b2f(v.y); acc2 += wgt*b2f(v.z); acc3 += wgt*b2f(v.w);
    }
    {
      ushort4 v = *(const ushort4*)&value[vbase + (r1+xc1)*256];
      float wgt = fx1*fy1;
      acc0 += wgt*b2f(v.x); acc1 += wgt*b2f(v.y); acc2 += wgt*b2f(v.z); acc3 += wgt*b2f(v.w);
    }
  }
  ushort4 o;
  o.x = f2b(acc0); o.y = f2b(acc1); o.z = f2b(acc2); o.w = f2b(acc3);
  *(ushort4*)&attn_out[(size_t)bn*256 + nh*64 + dg] = o;
}

// ---------------- K3: out-GEMM + bias + x residual + LN2 -> yt, res (64 rows/block)
__global__ __launch_bounds__(256) void k_out_ln(const u16* __restrict__ ain, // (B,N,C) bf16
      const u16* __restrict__ wo, const float* __restrict__ bo,
      const float* __restrict__ x,
      const float* __restrict__ g, const float* __restrict__ bta,
      u16* __restrict__ yt, u16* __restrict__ res) {
  __shared__ float pred[8192];          // sum[64][64] | sq[64][64]
  __shared__ float rmean[64], rstd[64];
  int t = threadIdx.x;
  int lane = t & 63, w = t >> 6;
  int blk = blockIdx.x;
  int b = blk >> 8;
  int n0 = (blk & 255) * 64;
  int l15 = lane & 15, lk = (lane >> 4) * 8;
  int rbase = (lane >> 4) * 4;
  f32x4 acc[4][4] = {};   // [mi][oj]
  float bias_v[4], gv[4], btv[4];
  #pragma unroll
  for (int oj = 0; oj < 4; ++oj) {
    int o = w*64 + oj*16 + l15;
    bias_v[oj] = bo[o]; gv[oj] = g[o]; btv[oj] = bta[o];
  }
  #pragma unroll
  for (int k0 = 0; k0 < 256; k0 += 32) {
    short8v af[4], bf[4];
    #pragma unroll
    for (int mi = 0; mi < 4; ++mi)
      af[mi] = *(const short8v*)&ain[(size_t)(b*N_DIM + n0 + mi*16 + l15)*256 + k0 + lk];
    #pragma unroll
    for (int oj = 0; oj < 4; ++oj)
      bf[oj] = *(const short8v*)&wo[(size_t)(w*64 + oj*16 + l15)*256 + k0 + lk];
    #pragma unroll
    for (int mi = 0; mi < 4; ++mi)
      #pragma unroll
      for (int oj = 0; oj < 4; ++oj)
        acc[mi][oj] = __builtin_amdgcn_mfma_f32_16x16x32_bf16(af[mi], bf[oj], acc[mi][oj], 0,0,0);
  }
  // bias + residual x
  #pragma unroll
  for (int mi = 0; mi < 4; ++mi)
    #pragma unroll
    for (int oj = 0; oj < 4; ++oj) {
      int o = w*64 + oj*16 + l15;
      const float* xp = &x[((size_t)(b*256 + o))*N_DIM + n0 + mi*16 + rbase];
      #pragma unroll
      for (int r = 0; r < 4; ++r)
        acc[mi][oj][r] += bias_v[oj] + xp[r];
    }
  // LN partial sums
  int cidx = w*16 + l15;
  #pragma unroll
  for (int mi = 0; mi < 4; ++mi)
    #pragma unroll
    for (int r = 0; r < 4; ++r) {
      int row = mi*16 + rbase + r;
      float s  = acc[mi][0][r] + acc[mi][1][r] + acc[mi][2][r] + acc[mi][3][r];
      float s2 = acc[mi][0][r]*acc[mi][0][r] + acc[mi][1][r]*acc[mi][1][r]
               + acc[mi][2][r]*acc[mi][2][r] + acc[mi][3][r]*acc[mi][3][r];
      pred[row*64 + cidx] = s;
      pred[4096 + row*64 + cidx] = s2;
    }
  __syncthreads();
  {
    int row = t >> 2, q = t & 3;
    float s = 0.f, s2 = 0.f;
    #pragma unroll
    for (int i = 0; i < 16; ++i) {
      s  += pred[row*64 + q*16 + i];
      s2 += pred[4096 + row*64 + q*16 + i];
    }
    s  += __shfl_xor(s, 1);  s  += __shfl_xor(s, 2);
    s2 += __shfl_xor(s2, 1); s2 += __shfl_xor(s2, 2);
    if (q == 0) {
      float m = s * (1.f/256.f);
      float var = s2 * (1.f/256.f) - m*m;
      rmean[row] = m; rstd[row] = rsqrtf(var + LN_EPSF);
    }
  }
  __syncthreads();
  // write res (pre-LN) and yt (post-LN), both (B,C,N) bf16
  #pragma unroll
  for (int mi = 0; mi < 4; ++mi)
    #pragma unroll
    for (int oj = 0; oj < 4; ++oj) {
      int o = w*64 + oj*16 + l15;
      size_t base = ((size_t)(b*256 + o))*N_DIM + n0 + mi*16 + rbase;
      ushort4 rv, yv;
      u16 rr[4], yy[4];
      #pragma unroll
      for (int r = 0; r < 4; ++r) {
        int row = mi*16 + rbase + r;
        float v = acc[mi][oj][r];
        rr[r] = f2b(v);
        yy[r] = f2b((v - rmean[row]) * rstd[row] * gv[oj] + btv[oj]);
      }
      rv.x=rr[0]; rv.y=rr[1]; rv.z=rr[2]; rv.w=rr[3];
      yv.x=yy[0]; yv.y=yy[1]; yv.z=yy[2]; yv.w=yy[3];
      *(ushort4*)&res[base] = rv;
      *(ushort4*)&yt[base]  = yv;
    }
}

// ---------------- K4: depthwise 3x3 + SiLU gate, vectorized (4 w / thread)
// Block: (b, c, hgrp of 8 rows). Thread: row r = t>>5, w4 = (t&31)*4.
__global__ __launch_bounds__(256) void k_dwconv(const u16* __restrict__ yt,
     const float* __restrict__ dww, const float* __restrict__ dwb,
     u16* __restrict__ hb) {
  int t = threadIdx.x;
  int blk = blockIdx.x;              // b*2048 + c*16 + hgrp
  int hg = blk & 15;
  int c  = (blk >> 4) & 127;
  int b  = blk >> 11;
  int r  = t >> 5;
  int wg = t & 31;
  int h  = hg*8 + r;
  int w4 = wg*4;
  const u16* p1 = yt + ((size_t)(b*256 + c))*N_DIM;
  const u16* p2 = yt + ((size_t)(b*256 + c + 128))*N_DIM;
  float w1[9], w2[9];
  #pragma unroll
  for (int i=0;i<9;++i){ w1[i]=dww[c*9+i]; w2[i]=dww[(c+128)*9+i]; }
  float a1[4], a2[4];
  #pragma unroll
  for (int j=0;j<4;++j){ a1[j]=dwb[c]; a2[j]=dwb[c+128]; }
  #pragma unroll
  for (int dy = 0; dy < 3; ++dy) {
    int yy = h + dy - 1;
    if (yy < 0 || yy >= H_DIM) continue;
    const u16* r1 = p1 + yy*W_DIM + w4;
    const u16* r2 = p2 + yy*W_DIM + w4;
    ushort4 m1 = *(const ushort4*)r1;
    ushort4 m2 = *(const ushort4*)r2;
    u16 l1 = wg ? r1[-1] : (u16)0;
    u16 l2 = wg ? r2[-1] : (u16)0;
    u16 q1 = (wg < 31) ? r1[4] : (u16)0;
    u16 q2 = (wg < 31) ? r2[4] : (u16)0;
    float v1[6] = { b2f(l1), b2f(m1.x), b2f(m1.y), b2f(m1.z), b2f(m1.w), b2f(q1) };
    float v2[6] = { b2f(l2), b2f(m2.x), b2f(m2.y), b2f(m2.z), b2f(m2.w), b2f(q2) };
    float t10 = w1[dy*3+0], t11 = w1[dy*3+1], t12 = w1[dy*3+2];
    float t20 = w2[dy*3+0], t21 = w2[dy*3+1], t22 = w2[dy*3+2];
    #pragma unroll
    for (int j = 0; j < 4; ++j) {
      a1[j] += t10*v1[j] + t11*v1[j+1] + t12*v1[j+2];
      a2[j] += t20*v2[j] + t21*v2[j+1] + t22*v2[j+2];
    }
  }
  ushort4 o;
  u16 ov[4];
  #pragma unroll
  for (int j = 0; j < 4; ++j) {
    float sig = 1.f/(1.f+expf(-a1[j]));
    ov[j] = f2b(a1[j]*sig*a2[j]);
  }
  o.x=ov[0]; o.y=ov[1]; o.z=ov[2]; o.w=ov[3];
  *(ushort4*)&hb[((size_t)(b*128+c))*N_DIM + h*W_DIM + w4] = o;
}

// ---------------- K5: d_out = pr_w @ h + pr_b + res(bf16)  (64-n tiles)
__global__ __launch_bounds__(256) void k_prfinal_mfma(const u16* __restrict__ hsrc,
     const u16* __restrict__ pw, const float* __restrict__ prb,
     const u16* __restrict__ resb, float* __restrict__ dout) {
  __shared__ u16 hls[64*128];      // [n][k], k XOR-swizzled by ((n&7)<<3)
  int t = threadIdx.x;
  int lane = t & 63, w = t >> 6;
  int b = blockIdx.y;
  int n0 = blockIdx.x * 64;
  #pragma unroll
  for (int r = 0; r < 4; ++r) {
    int e = t + 256*r;
    int k = e >> 3;
    int n8 = (e & 7) * 8;
    short8v v = *(const short8v*)&hsrc[((size_t)(b*128 + k))*N_DIM + n0 + n8];
    #pragma unroll
    for (int j = 0; j < 8; ++j) {
      int n = n8 + j;
      hls[n*128 + (k ^ ((n & 7) << 3))] = (u16)v[j];
    }
  }
  __syncthreads();
  int l15 = lane & 15, lk = (lane >> 4) * 8;
  f32x4 acc[4][4] = {};
  #pragma unroll
  for (int k0 = 0; k0 < 128; k0 += 32) {
    short8v af[4], bf[4];
    #pragma unroll
    for (int oi = 0; oi < 4; ++oi)
      af[oi] = *(const short8v*)&pw[(size_t)(w*64 + oi*16 + l15)*128 + k0 + lk];
    #pragma unroll
    for (int nj = 0; nj < 4; ++nj) {
      int n = nj*16 + l15;
      bf[nj] = *(const short8v*)&hls[n*128 + ((k0 + lk) ^ ((n & 7) << 3))];
    }
    #pragma unroll
    for (int oi = 0; oi < 4; ++oi)
      #pragma unroll
      for (int nj = 0; nj < 4; ++nj)
        acc[oi][nj] = __builtin_amdgcn_mfma_f32_16x16x32_bf16(af[oi], bf[nj], acc[oi][nj], 0,0,0);
  }
  int rbase = (lane >> 4) * 4;
  #pragma unroll
  for (int oi = 0; oi < 4; ++oi)
    #pragma unroll
    for (int r = 0; r < 4; ++r) {
      int o = w*64 + oi*16 + rbase + r;
      float pb = prb[o];
      #pragma unroll
      for (int nj = 0; nj < 4; ++nj) {
        int n = n0 + nj*16 + l15;
        size_t idx = ((size_t)(b*256 + o))*N_DIM + n;
        dout[idx] = acc[oi][nj][r] + pb + b2f(resb[idx]);
      }
    }
}

extern "C" void kernel_launch(void* const* d_in, const int* in_sizes, int n_in,
                              void* d_out, int out_size, void* d_ws, size_t ws_size,
                              hipStream_t stream) {
  const float* x      = (const float*)d_in[0];
  const float* norm_g = (const float*)d_in[1];
  const float* norm_b = (const float*)d_in[2];
  const float* ffn_g  = (const float*)d_in[3];
  const float* ffn_b  = (const float*)d_in[4];
  const float* W_val  = (const float*)d_in[5];
  const float* b_val  = (const float*)d_in[6];
  const float* W_off  = (const float*)d_in[7];
  const float* b_off  = (const float*)d_in[8];
  const float* W_attn = (const float*)d_in[9];
  const float* b_attn = (const float*)d_in[10];
  const float* W_out  = (const float*)d_in[11];
  const float* b_out  = (const float*)d_in[12];
  const float* dw_w   = (const float*)d_in[13];
  const float* dw_b   = (const float*)d_in[14];
  const float* pr_w   = (const float*)d_in[15];
  const float* pr_b   = (const float*)d_in[16];
  float* outp = (float*)d_out;

  char* ws = (char*)d_ws;
  const size_t MB = 1u << 20;
  u16*   valbf  = (u16*)(ws);
  u16*   attnbf = (u16*)(ws + 17*MB);
  u16*   resbf  = (u16*)(ws + 34*MB);
  u16*   ytbf   = (u16*)(ws + 51*MB);
  u16*   hbuf   = (u16*)(ws + 68*MB);
  float* boffb  = (float*)(ws + 77*MB);
  float* bawb   = (float*)(ws + 82*MB);
  u16*   wvbf   = (u16*)(ws + 85*MB);
  u16*   wobf   = (u16*)(ws + 85*MB + 131072u);
  u16*   pwbf   = (u16*)(ws + 85*MB + 262144u);
  u16*   wabbf  = (u16*)(ws + 85*MB + 327680u);

  // 0. weights -> bf16
  k_cvt5<<<dim3(172), dim3(256), 0, stream>>>(W_val, W_out, pr_w, W_off, W_attn,
                                              wvbf, wobf, pwbf, wabbf);
  // 1. LN1 + value GEMM + off/attn GEMM (q stays in LDS)
  k_fused1<<<dim3(512), dim3(256), 0, stream>>>(x, norm_g, norm_b, wvbf, b_val,
                                                wabbf, b_off, b_attn,
                                                valbf, boffb, bawb);
  // 2. standalone sampling (XCD-swizzled, high occupancy)
  k_sample<<<dim3(8192), dim3(256), 0, stream>>>(valbf, boffb, bawb, attnbf);
  // 3. out-GEMM + residual + LN2 -> yt, res
  k_out_ln<<<dim3(512), dim3(256), 0, stream>>>(attnbf, wobf, b_out,
                                                x, ffn_g, ffn_b, ytbf, resbf);
  // 4. depthwise conv + SiLU gate (vectorized, 4 w/thread)
  k_dwconv<<<dim3(4096), dim3(256), 0, stream>>>(ytbf, dw_w, dw_b, hbuf);
  // 5. d_out = pr_w @ h + pr_b + res
  k_prfinal_mfma<<<dim3(256, 2), dim3(256), 0, stream>>>(hbuf, pwbf, pr_b, resbf, outp);

  (void)in_sizes; (void)n_in; (void)out_size; (void)ws_size;
}

// Round 12
// 118.606 us; speedup vs baseline: 1.1517x; 1.0133x over previous
//
#include <hip/hip_runtime.h>
#include <cmath>

typedef unsigned short u16;
typedef __attribute__((ext_vector_type(8))) short short8v;   // 8 bf16
typedef __attribute__((ext_vector_type(4))) float f32x4;

#define C_DIM 256
#define H_DIM 128
#define W_DIM 128
#define N_DIM (H_DIM*W_DIM)   // 16384
#define B_DIM 2
#define LN_EPSF 1e-5f

__device__ __forceinline__ u16 f2b(float f) {
  unsigned u = __float_as_uint(f);
  unsigned r = (u + 0x7fffu + ((u >> 16) & 1u)) >> 16;   // RNE
  return (u16)r;
}
__device__ __forceinline__ float b2f(u16 h) {
  return __uint_as_float(((unsigned)h) << 16);
}

// ---------------- K0: f32 -> bf16 conversion: W_val, W_out, pr_w, W_off|W_attn
__global__ __launch_bounds__(256) void k_cvt5(const float* __restrict__ w0,
      const float* __restrict__ w1, const float* __restrict__ w2,
      const float* __restrict__ w3, const float* __restrict__ w4,
      u16* __restrict__ d0, u16* __restrict__ d1, u16* __restrict__ d2,
      u16* __restrict__ d3) {
  int i = blockIdx.x*256 + threadIdx.x;   // float4 index
  const float* s; u16* d; int l;
  if (i < 16384)      { s = w0; d = d0;        l = i; }
  else if (i < 32768) { s = w1; d = d1;        l = i - 16384; }
  else if (i < 40960) { s = w2; d = d2;        l = i - 32768; }
  else if (i < 43008) { s = w3; d = d3;        l = i - 40960; }
  else if (i < 44032) { s = w4; d = d3 + 8192; l = i - 43008; }
  else return;
  float4 v = *(const float4*)&s[(size_t)l*4];
  d[l*4+0]=f2b(v.x); d[l*4+1]=f2b(v.y); d[l*4+2]=f2b(v.z); d[l*4+3]=f2b(v.w);
}

// ---------------- K1: fused LN1 + value GEMM + off/attn GEMM + softmax (64 rows/block)
// LN tile staged in bf16 -> LDS ~51 KB -> 3 blocks/CU.
__global__ __launch_bounds__(256) void k_fused1(const float* __restrict__ x,
      const float* __restrict__ g, const float* __restrict__ bta,
      const u16* __restrict__ wv, const float* __restrict__ bval,
      const u16* __restrict__ wab, const float* __restrict__ boff,
      const float* __restrict__ battn,
      u16* __restrict__ val, float* __restrict__ off, float* __restrict__ aw) {
  __shared__ u16  tileb[256*33];     // [c][nl] bf16, padded
  __shared__ float psum[256], psq[256];
  __shared__ float rmean[32], rstd[32];
  __shared__ u16 qls[64*256];        // [n][k], k XOR-swizzled by ((n&7)<<3)
  int t = threadIdx.x;
  int blk = blockIdx.x;
  int b = blk >> 8;
  int n0 = (blk & 255) * 64;
  for (int half = 0; half < 2; ++half) {
    int nh0 = n0 + half*32;
    int nl = t & 31, cr = t >> 5;
    #pragma unroll 4
    for (int i = 0; i < 32; ++i) {
      int c = i*8 + cr;
      tileb[c*33 + nl] = f2b(x[((size_t)(b*C_DIM + c))*N_DIM + nh0 + nl]);
    }
    __syncthreads();
    {
      int n = t & 31, j = t >> 5;
      float s = 0.f, s2 = 0.f;
      #pragma unroll 8
      for (int i = 0; i < 32; ++i) {
        float v = b2f(tileb[(j*32+i)*33 + n]);
        s += v; s2 += v*v;
      }
      psum[j*32+n] = s; psq[j*32+n] = s2;
    }
    __syncthreads();
    if (t < 32) {
      float s=0.f, s2=0.f;
      for (int j=0;j<8;++j){ s += psum[j*32+t]; s2 += psq[j*32+t]; }
      float m = s * (1.f/256.f);
      float var = s2 * (1.f/256.f) - m*m;
      rmean[t] = m; rstd[t] = rsqrtf(var + LN_EPSF);
    }
    __syncthreads();
    float gt = g[t], bt = bta[t];
    #pragma unroll 4
    for (int i = 0; i < 32; ++i) {
      float v = b2f(tileb[t*33 + i]);
      int n = half*32 + i;
      qls[n*256 + (t ^ ((n & 7) << 3))] = f2b((v - rmean[i]) * rstd[i] * gt + bt);
    }
    __syncthreads();
  }
  int lane = t & 63, w = t >> 6;
  int l15 = lane & 15, lk = (lane >> 4) * 8;
  f32x4 acc[4][4] = {};
  f32x4 acc_oa[4] = {};
  float bias_v[4];
  #pragma unroll
  for (int oj = 0; oj < 4; ++oj) bias_v[oj] = bval[w*64 + oj*16 + l15];
  #pragma unroll
  for (int k0 = 0; k0 < 256; k0 += 32) {
    short8v af[4], bf[4];
    #pragma unroll
    for (int mi = 0; mi < 4; ++mi) {
      int n = mi*16 + l15;
      af[mi] = *(const short8v*)&qls[n*256 + ((k0 + lk) ^ ((n & 7) << 3))];
    }
    #pragma unroll
    for (int oj = 0; oj < 4; ++oj)
      bf[oj] = *(const short8v*)&wv[(size_t)(w*64 + oj*16 + l15)*256 + k0 + lk];
    #pragma unroll
    for (int mi = 0; mi < 4; ++mi)
      #pragma unroll
      for (int oj = 0; oj < 4; ++oj)
        acc[mi][oj] = __builtin_amdgcn_mfma_f32_16x16x32_bf16(af[mi], bf[oj], acc[mi][oj], 0,0,0);
    if (w < 3) {
      short8v bw = *(const short8v*)&wab[(size_t)(w*16 + l15)*256 + k0 + lk];
      #pragma unroll
      for (int mi = 0; mi < 4; ++mi)
        acc_oa[mi] = __builtin_amdgcn_mfma_f32_16x16x32_bf16(af[mi], bw, acc_oa[mi], 0,0,0);
    }
  }
  int rbase = (lane >> 4) * 4;
  #pragma unroll
  for (int mi = 0; mi < 4; ++mi)
    #pragma unroll
    for (int oj = 0; oj < 4; ++oj)
      #pragma unroll
      for (int r = 0; r < 4; ++r) {
        size_t m = (size_t)(b*N_DIM + n0 + mi*16 + rbase + r);
        int o = w*64 + oj*16 + l15;
        val[m*256 + o] = f2b(acc[mi][oj][r] + bias_v[oj]);
      }
  if (w < 2) {
    int o = w*16 + l15;
    float bv2 = boff[o];
    #pragma unroll
    for (int mi = 0; mi < 4; ++mi)
      #pragma unroll
      for (int r = 0; r < 4; ++r) {
        size_t m = (size_t)(b*N_DIM + n0 + mi*16 + rbase + r);
        off[m*32 + o] = acc_oa[mi][r] + bv2;
      }
  } else if (w == 2) {
    float bv2 = battn[l15];
    #pragma unroll
    for (int mi = 0; mi < 4; ++mi)
      #pragma unroll
      for (int r = 0; r < 4; ++r) {
        float v = acc_oa[mi][r] + bv2;
        float mx = fmaxf(v, __shfl_xor(v, 1));
        mx = fmaxf(mx, __shfl_xor(mx, 2));
        float e = expf(v - mx);
        float s = e + __shfl_xor(e, 1);
        s = s + __shfl_xor(s, 2);
        size_t m = (size_t)(b*N_DIM + n0 + mi*16 + rbase + r);
        aw[m*16 + l15] = e / s;
      }
  }
}

// ---------------- K2: standalone deformable sampling (wave per bn), XCD-swizzled
__global__ __launch_bounds__(256) void k_sample(const u16* __restrict__ value,
      const float* __restrict__ off, const float* __restrict__ aw,
      u16* __restrict__ attn_out) {
  int t = threadIdx.x;
  int wv = t >> 6, lane = t & 63;
  int orig = blockIdx.x;                      // 8192 blocks, %8==0 -> bijective
  int id = (orig & 7) * 1024 + (orig >> 3);   // contiguous 1024-block chunk per XCD
  int bn = id*4 + wv;                         // b*N + n
  int b = bn >> 14, n = bn & (N_DIM-1);
  int hc = n >> 7, wc = n & 127;
  int nh = lane >> 4;
  int dg = (lane & 15) * 4;
  int vbase = b*(N_DIM*256) + nh*64 + dg;
  const float* op = &off[(size_t)bn*32 + nh*8];
  const float* ap = &aw[(size_t)bn*16 + nh*4];
  float acc0=0.f, acc1=0.f, acc2=0.f, acc3=0.f;
  #pragma unroll
  for (int p = 0; p < 4; ++p) {
    float ox = op[p*2+0], oy = op[p*2+1];
    float a  = ap[p];
    float px = (float)wc + ox;
    float py = (float)hc + oy;
    float x0f = floorf(px), y0f = floorf(py);
    float wx = px - x0f, wy = py - y0f;
    int x0 = (int)x0f, y0 = (int)y0f;
    int x1 = x0 + 1, y1 = y0 + 1;
    float fx0 = (1.f - wx) * ((x0 >= 0 && x0 < W_DIM) ? 1.f : 0.f);
    float fx1 = wx         * ((x1 >= 0 && x1 < W_DIM) ? 1.f : 0.f);
    float fy0 = a * (1.f - wy) * ((y0 >= 0 && y0 < H_DIM) ? 1.f : 0.f);
    float fy1 = a * wy         * ((y1 >= 0 && y1 < H_DIM) ? 1.f : 0.f);
    int xc0 = min(max(x0,0),W_DIM-1), xc1 = min(max(x1,0),W_DIM-1);
    int yc0 = min(max(y0,0),H_DIM-1), yc1 = min(max(y1,0),H_DIM-1);
    int r0 = yc0*W_DIM, r1 = yc1*W_DIM;
    {
      ushort4 v = *(const ushort4*)&value[vbase + (r0+xc0)*256];
      float wgt = fx0*fy0;
      acc0 += wgt*b2f(v.x); acc1 += wgt*b2f(v.y); acc2 += wgt*b2f(v.z); acc3 += wgt*b2f(v.w);
    }
    {
      ushort4 v = *(const ushort4*)&value[vbase + (r0+xc1)*256];
      float wgt = fx1*fy0;
      acc0 += wgt*b2f(v.x); acc1 += wgt*b2f(v.y); acc2 += wgt*b2f(v.z); acc3 += wgt*b2f(v.w);
    }
    {
      ushort4 v = *(const ushort4*)&value[vbase + (r1+xc0)*256];
      float wgt = fx0*fy1;
      acc0 += wgt*b2f(v.x); acc1 += wgt*b2f(v.y); acc2 += wgt*b2f(v.z); acc3 += wgt*b2f(v.w);
    }
    {
      ushort4 v = *(const ushort4*)&value[vbase + (r1+xc1)*256];
      float wgt = fx1*fy1;
      acc0 += wgt*b2f(v.x); acc1 += wgt*b2f(v.y); acc2 += wgt*b2f(v.z); acc3 += wgt*b2f(v.w);
    }
  }
  ushort4 o;
  o.x = f2b(acc0); o.y = f2b(acc1); o.z = f2b(acc2); o.w = f2b(acc3);
  *(ushort4*)&attn_out[(size_t)bn*256 + nh*64 + dg] = o;
}

// ---------------- K3: out-GEMM + bias + x residual + LN2 -> yt, res (64 rows/block)
// LN reduction via in-wave shfl (lanes sharing a row differ only in bits 0-3) + 2 KB LDS.
__global__ __launch_bounds__(256) void k_out_ln(const u16* __restrict__ ain, // (B,N,C) bf16
      const u16* __restrict__ wo, const float* __restrict__ bo,
      const float* __restrict__ x,
      const float* __restrict__ g, const float* __restrict__ bta,
      u16* __restrict__ yt, u16* __restrict__ res) {
  __shared__ float red[64*4], red2[64*4];   // [row][wave]
  __shared__ float rmean[64], rstd[64];
  int t = threadIdx.x;
  int lane = t & 63, w = t >> 6;
  int blk = blockIdx.x;
  int b = blk >> 8;
  int n0 = (blk & 255) * 64;
  int l15 = lane & 15, lk = (lane >> 4) * 8;
  int rbase = (lane >> 4) * 4;
  f32x4 acc[4][4] = {};   // [mi][oj]
  float bias_v[4], gv[4], btv[4];
  #pragma unroll
  for (int oj = 0; oj < 4; ++oj) {
    int o = w*64 + oj*16 + l15;
    bias_v[oj] = bo[o]; gv[oj] = g[o]; btv[oj] = bta[o];
  }
  #pragma unroll
  for (int k0 = 0; k0 < 256; k0 += 32) {
    short8v af[4], bf[4];
    #pragma unroll
    for (int mi = 0; mi < 4; ++mi)
      af[mi] = *(const short8v*)&ain[(size_t)(b*N_DIM + n0 + mi*16 + l15)*256 + k0 + lk];
    #pragma unroll
    for (int oj = 0; oj < 4; ++oj)
      bf[oj] = *(const short8v*)&wo[(size_t)(w*64 + oj*16 + l15)*256 + k0 + lk];
    #pragma unroll
    for (int mi = 0; mi < 4; ++mi)
      #pragma unroll
      for (int oj = 0; oj < 4; ++oj)
        acc[mi][oj] = __builtin_amdgcn_mfma_f32_16x16x32_bf16(af[mi], bf[oj], acc[mi][oj], 0,0,0);
  }
  // bias + residual x
  #pragma unroll
  for (int mi = 0; mi < 4; ++mi)
    #pragma unroll
    for (int oj = 0; oj < 4; ++oj) {
      int o = w*64 + oj*16 + l15;
      const float* xp = &x[((size_t)(b*256 + o))*N_DIM + n0 + mi*16 + rbase];
      #pragma unroll
      for (int r = 0; r < 4; ++r)
        acc[mi][oj][r] += bias_v[oj] + xp[r];
    }
  // LN partial sums: shfl-reduce across the 16 lanes (bits 0-3) sharing each row
  #pragma unroll
  for (int mi = 0; mi < 4; ++mi)
    #pragma unroll
    for (int r = 0; r < 4; ++r) {
      int row = mi*16 + rbase + r;
      float s  = acc[mi][0][r] + acc[mi][1][r] + acc[mi][2][r] + acc[mi][3][r];
      float s2 = acc[mi][0][r]*acc[mi][0][r] + acc[mi][1][r]*acc[mi][1][r]
               + acc[mi][2][r]*acc[mi][2][r] + acc[mi][3][r]*acc[mi][3][r];
      s  += __shfl_xor(s, 1);  s  += __shfl_xor(s, 2);
      s  += __shfl_xor(s, 4);  s  += __shfl_xor(s, 8);
      s2 += __shfl_xor(s2, 1); s2 += __shfl_xor(s2, 2);
      s2 += __shfl_xor(s2, 4); s2 += __shfl_xor(s2, 8);
      if (l15 == 0) { red[row*4 + w] = s; red2[row*4 + w] = s2; }
    }
  __syncthreads();
  if (t < 64) {
    float s  = red[t*4+0]  + red[t*4+1]  + red[t*4+2]  + red[t*4+3];
    float s2 = red2[t*4+0] + red2[t*4+1] + red2[t*4+2] + red2[t*4+3];
    float m = s * (1.f/256.f);
    float var = s2 * (1.f/256.f) - m*m;
    rmean[t] = m; rstd[t] = rsqrtf(var + LN_EPSF);
  }
  __syncthreads();
  // write res (pre-LN) and yt (post-LN), both (B,C,N) bf16
  #pragma unroll
  for (int mi = 0; mi < 4; ++mi)
    #pragma unroll
    for (int oj = 0; oj < 4; ++oj) {
      int o = w*64 + oj*16 + l15;
      size_t base = ((size_t)(b*256 + o))*N_DIM + n0 + mi*16 + rbase;
      ushort4 rv, yv;
      u16 rr[4], yy[4];
      #pragma unroll
      for (int r = 0; r < 4; ++r) {
        int row = mi*16 + rbase + r;
        float v = acc[mi][oj][r];
        rr[r] = f2b(v);
        yy[r] = f2b((v - rmean[row]) * rstd[row] * gv[oj] + btv[oj]);
      }
      rv.x=rr[0]; rv.y=rr[1]; rv.z=rr[2]; rv.w=rr[3];
      yv.x=yy[0]; yv.y=yy[1]; yv.z=yy[2]; yv.w=yy[3];
      *(ushort4*)&res[base] = rv;
      *(ushort4*)&yt[base]  = yv;
    }
}

// ---------------- K4: depthwise 3x3 + SiLU gate, vectorized (4 w / thread)
__global__ __launch_bounds__(256) void k_dwconv(const u16* __restrict__ yt,
     const float* __restrict__ dww, const float* __restrict__ dwb,
     u16* __restrict__ hb) {
  int t = threadIdx.x;
  int blk = blockIdx.x;              // b*2048 + c*16 + hgrp
  int hg = blk & 15;
  int c  = (blk >> 4) & 127;
  int b  = blk >> 11;
  int r  = t >> 5;
  int wg = t & 31;
  int h  = hg*8 + r;
  int w4 = wg*4;
  const u16* p1 = yt + ((size_t)(b*256 + c))*N_DIM;
  const u16* p2 = yt + ((size_t)(b*256 + c + 128))*N_DIM;
  float w1[9], w2[9];
  #pragma unroll
  for (int i=0;i<9;++i){ w1[i]=dww[c*9+i]; w2[i]=dww[(c+128)*9+i]; }
  float a1[4], a2[4];
  #pragma unroll
  for (int j=0;j<4;++j){ a1[j]=dwb[c]; a2[j]=dwb[c+128]; }
  #pragma unroll
  for (int dy = 0; dy < 3; ++dy) {
    int yy = h + dy - 1;
    if (yy < 0 || yy >= H_DIM) continue;
    const u16* r1 = p1 + yy*W_DIM + w4;
    const u16* r2 = p2 + yy*W_DIM + w4;
    ushort4 m1 = *(const ushort4*)r1;
    ushort4 m2 = *(const ushort4*)r2;
    u16 l1 = wg ? r1[-1] : (u16)0;
    u16 l2 = wg ? r2[-1] : (u16)0;
    u16 q1 = (wg < 31) ? r1[4] : (u16)0;
    u16 q2 = (wg < 31) ? r2[4] : (u16)0;
    float v1[6] = { b2f(l1), b2f(m1.x), b2f(m1.y), b2f(m1.z), b2f(m1.w), b2f(q1) };
    float v2[6] = { b2f(l2), b2f(m2.x), b2f(m2.y), b2f(m2.z), b2f(m2.w), b2f(q2) };
    float t10 = w1[dy*3+0], t11 = w1[dy*3+1], t12 = w1[dy*3+2];
    float t20 = w2[dy*3+0], t21 = w2[dy*3+1], t22 = w2[dy*3+2];
    #pragma unroll
    for (int j = 0; j < 4; ++j) {
      a1[j] += t10*v1[j] + t11*v1[j+1] + t12*v1[j+2];
      a2[j] += t20*v2[j] + t21*v2[j+1] + t22*v2[j+2];
    }
  }
  ushort4 o;
  u16 ov[4];
  #pragma unroll
  for (int j = 0; j < 4; ++j) {
    float sig = 1.f/(1.f+expf(-a1[j]));
    ov[j] = f2b(a1[j]*sig*a2[j]);
  }
  o.x=ov[0]; o.y=ov[1]; o.z=ov[2]; o.w=ov[3];
  *(ushort4*)&hb[((size_t)(b*128+c))*N_DIM + h*W_DIM + w4] = o;
}

// ---------------- K5: d_out = pr_w @ h + pr_b + res(bf16)  (64-n tiles)
__global__ __launch_bounds__(256) void k_prfinal_mfma(const u16* __restrict__ hsrc,
     const u16* __restrict__ pw, const float* __restrict__ prb,
     const u16* __restrict__ resb, float* __restrict__ dout) {
  __shared__ u16 hls[64*128];      // [n][k], k XOR-swizzled by ((n&7)<<3)
  int t = threadIdx.x;
  int lane = t & 63, w = t >> 6;
  int b = blockIdx.y;
  int n0 = blockIdx.x * 64;
  #pragma unroll
  for (int r = 0; r < 4; ++r) {
    int e = t + 256*r;
    int k = e >> 3;
    int n8 = (e & 7) * 8;
    short8v v = *(const short8v*)&hsrc[((size_t)(b*128 + k))*N_DIM + n0 + n8];
    #pragma unroll
    for (int j = 0; j < 8; ++j) {
      int n = n8 + j;
      hls[n*128 + (k ^ ((n & 7) << 3))] = (u16)v[j];
    }
  }
  __syncthreads();
  int l15 = lane & 15, lk = (lane >> 4) * 8;
  f32x4 acc[4][4] = {};
  #pragma unroll
  for (int k0 = 0; k0 < 128; k0 += 32) {
    short8v af[4], bf[4];
    #pragma unroll
    for (int oi = 0; oi < 4; ++oi)
      af[oi] = *(const short8v*)&pw[(size_t)(w*64 + oi*16 + l15)*128 + k0 + lk];
    #pragma unroll
    for (int nj = 0; nj < 4; ++nj) {
      int n = nj*16 + l15;
      bf[nj] = *(const short8v*)&hls[n*128 + ((k0 + lk) ^ ((n & 7) << 3))];
    }
    #pragma unroll
    for (int oi = 0; oi < 4; ++oi)
      #pragma unroll
      for (int nj = 0; nj < 4; ++nj)
        acc[oi][nj] = __builtin_amdgcn_mfma_f32_16x16x32_bf16(af[oi], bf[nj], acc[oi][nj], 0,0,0);
  }
  int rbase = (lane >> 4) * 4;
  #pragma unroll
  for (int oi = 0; oi < 4; ++oi)
    #pragma unroll
    for (int r = 0; r < 4; ++r) {
      int o = w*64 + oi*16 + rbase + r;
      float pb = prb[o];
      #pragma unroll
      for (int nj = 0; nj < 4; ++nj) {
        int n = n0 + nj*16 + l15;
        size_t idx = ((size_t)(b*256 + o))*N_DIM + n;
        dout[idx] = acc[oi][nj][r] + pb + b2f(resb[idx]);
      }
    }
}

extern "C" void kernel_launch(void* const* d_in, const int* in_sizes, int n_in,
                              void* d_out, int out_size, void* d_ws, size_t ws_size,
                              hipStream_t stream) {
  const float* x      = (const float*)d_in[0];
  const float* norm_g = (const float*)d_in[1];
  const float* norm_b = (const float*)d_in[2];
  const float* ffn_g  = (const float*)d_in[3];
  const float* ffn_b  = (const float*)d_in[4];
  const float* W_val  = (const float*)d_in[5];
  const float* b_val  = (const float*)d_in[6];
  const float* W_off  = (const float*)d_in[7];
  const float* b_off  = (const float*)d_in[8];
  const float* W_attn = (const float*)d_in[9];
  const float* b_attn = (const float*)d_in[10];
  const float* W_out  = (const float*)d_in[11];
  const float* b_out  = (const float*)d_in[12];
  const float* dw_w   = (const float*)d_in[13];
  const float* dw_b   = (const float*)d_in[14];
  const float* pr_w   = (const float*)d_in[15];
  const float* pr_b   = (const float*)d_in[16];
  float* outp = (float*)d_out;

  char* ws = (char*)d_ws;
  const size_t MB = 1u << 20;
  u16*   valbf  = (u16*)(ws);
  u16*   attnbf = (u16*)(ws + 17*MB);
  u16*   resbf  = (u16*)(ws + 34*MB);
  u16*   ytbf   = (u16*)(ws + 51*MB);
  u16*   hbuf   = (u16*)(ws + 68*MB);
  float* boffb  = (float*)(ws + 77*MB);
  float* bawb   = (float*)(ws + 82*MB);
  u16*   wvbf   = (u16*)(ws + 85*MB);
  u16*   wobf   = (u16*)(ws + 85*MB + 131072u);
  u16*   pwbf   = (u16*)(ws + 85*MB + 262144u);
  u16*   wabbf  = (u16*)(ws + 85*MB + 327680u);

  // 0. weights -> bf16
  k_cvt5<<<dim3(172), dim3(256), 0, stream>>>(W_val, W_out, pr_w, W_off, W_attn,
                                              wvbf, wobf, pwbf, wabbf);
  // 1. LN1 + value GEMM + off/attn GEMM (q stays in LDS)
  k_fused1<<<dim3(512), dim3(256), 0, stream>>>(x, norm_g, norm_b, wvbf, b_val,
                                                wabbf, b_off, b_attn,
                                                valbf, boffb, bawb);
  // 2. standalone sampling (XCD-swizzled, high occupancy)
  k_sample<<<dim3(8192), dim3(256), 0, stream>>>(valbf, boffb, bawb, attnbf);
  // 3. out-GEMM + residual + LN2 -> yt, res
  k_out_ln<<<dim3(512), dim3(256), 0, stream>>>(attnbf, wobf, b_out,
                                                x, ffn_g, ffn_b, ytbf, resbf);
  // 4. depthwise conv + SiLU gate (vectorized, 4 w/thread)
  k_dwconv<<<dim3(4096), dim3(256), 0, stream>>>(ytbf, dw_w, dw_b, hbuf);
  // 5. d_out = pr_w @ h + pr_b + res
  k_prfinal_mfma<<<dim3(256, 2), dim3(256), 0, stream>>>(hbuf, pwbf, pr_b, resbf, outp);

  (void)in_sizes; (void)n_in; (void)out_size; (void)ws_size;
}